// Round 15
// baseline (22411.913 us; speedup 1.0000x reference)
//
#include <hip/hip_runtime.h>

// RNN echo-state scan on MI355X — round 15: ONE group of 16 WGs, M=64.
// Protocol (proven r2/r6/r9/r12/r14): sc1 write-through publish -> vmcnt(0)
// drain at __syncthreads -> ONE agent-atomic post per WG (own slot); consumer
// wave0 lanes<16 poll slots -> wave0 acquire-fence -> __syncthreads -> plain
// batched loads.
// New vs r14: 16 WGs total (not 128). Each WG: 64 cols x ALL 64 batches
// (4 m-tiles — honest M=64, halves total MFMA vs the padded M=8->16 scheme).
// Fence count drops 128 -> 16 per step (2 per XCD) — tests the inv-storm
// hypothesis for the unexplained ~60% of step time. A-tile 128KB/WG streamed
// via 3-slot 2-block-lookahead pipeline (<=16 loads in flight, no spill).

#define TT    2048
#define BB    64
#define NIN   64
#define NRECN 1024
#define KTOT  1088
#define NWG   16
#define NOISE_STD 0.001f

typedef __attribute__((ext_vector_type(8))) _Float16 half8;
typedef __attribute__((ext_vector_type(4))) float f32x4;
typedef __attribute__((ext_vector_type(2))) unsigned int u32x2;

__device__ __forceinline__ void st_d2_sc1(void* p, u32x2 w) {
  asm volatile("global_store_dwordx2 %0, %1, off sc1" :: "v"(p), "v"(w) : "memory");
}
__device__ __forceinline__ unsigned pk2h(float a, float b) {
  unsigned short ua = __builtin_bit_cast(unsigned short, (_Float16)a);
  unsigned short ub = __builtin_bit_cast(unsigned short, (_Float16)b);
  return (unsigned)ua | ((unsigned)ub << 16);
}
__device__ __forceinline__ half8 cvt8(const f32x4& a, const f32x4& b) {
  half8 r;
  #pragma unroll
  for (int j = 0; j < 4; ++j) { r[j] = (_Float16)a[j]; r[4+j] = (_Float16)b[j]; }
  return r;
}

#define LDA16(V, P, OFF) \
  asm volatile("global_load_dwordx4 %0, %1, off offset:%c2" \
               : "=&v"(V) : "v"(P), "n"(OFF))
#define WAITV(N) asm volatile("s_waitcnt vmcnt(" #N ")" ::: "memory")
#define SB0 __builtin_amdgcn_sched_barrier(0)
#define MFMA16 __builtin_amdgcn_mfma_f32_16x16x32_f16

// Issue block b (K-chunks 2b,2b+1) for all 4 m-tiles into slot s (8 loads).
#define ISSUE(b, s) do {                                           \
    _Pragma("unroll")                                              \
    for (int m_ = 0; m_ < 4; ++m_) {                               \
      LDA16(A[s][0 * 4 + m_], ab[m_], (2 * (b)) * 64);             \
      LDA16(A[s][1 * 4 + m_], ab[m_], (2 * (b) + 1) * 64);         \
    } } while (0)

// Consume block b from slot s: per chunk read W once, feed 4 m-tiles.
#define COMPUTE(b, s) do {                                         \
    _Pragma("unroll")                                              \
    for (int i2_ = 0; i2_ < 2; ++i2_) {                            \
      const int c_ = 2 * (b) + i2_;                                \
      half8 w0_ = *(const half8*)(whp0 + c_ * 2048);               \
      half8 w1_ = *(const half8*)(whp1 + c_ * 2048);               \
      _Pragma("unroll")                                            \
      for (int m_ = 0; m_ < 4; ++m_) {                             \
        acc0[m_] = MFMA16(w0_, A[s][i2_ * 4 + m_], acc0[m_], 0, 0, 0); \
        acc1[m_] = MFMA16(w1_, A[s][i2_ * 4 + m_], acc1[m_], 0, 0, 0); \
      } } } while (0)

#define STEPB(b, WN) do {                                          \
    WAITV(WN); SB0;                                                \
    if ((b) + 2 < 16) ISSUE((b) + 2, ((b) + 2) % 3);               \
    COMPUTE(b, (b) % 3); } while (0)

__global__ __launch_bounds__(128, 1) void rnn_scan_kernel(
    const float* __restrict__ x, const float* __restrict__ W_ih,
    const float* __restrict__ W_hh, const float* __restrict__ noise,
    float* __restrict__ out, int* __restrict__ flags,
    _Float16* __restrict__ th)
{
  extern __shared__ _Float16 smem[];   // W f16, sub-chunk-major [136][64][8]

  const int wg = blockIdx.x;
  const int tid = threadIdx.x, lane = tid & 63, wv = tid >> 6;
  const int l15 = lane & 15, g4 = lane >> 4;

  // one-time: W slice (cols wg*64..+64, K=1088) -> LDS f16 (r12/r14 layout)
  for (int idx = tid; idx < 64 * KTOT; idx += 128) {
    int nr = idx / KTOT, k = idx - nr * KTOT;
    int ng = wg * 64 + nr;
    float v = (k < NRECN) ? W_hh[(size_t)ng * NRECN + k]
                          : W_ih[(size_t)ng * NIN + (k - NRECN)];
    smem[(k >> 3) * 512 + nr * 8 + (k & 7)] = (_Float16)v;
  }
  __syncthreads();

  const _Float16* whp0 = smem + g4 * 512 + (wv * 32 + l15) * 8; // +c*2048
  const _Float16* whp1 = whp0 + 128;
  const int cB = wg * 64 + wv * 32 + g4 * 4;    // lane's 4-col base (frag0)

  // per-m-tile base pointers (batch = m*16 + l15)
  const float* xr[4];
  #pragma unroll
  for (int m = 0; m < 4; ++m)
    xr[m] = x + (size_t)(m * 16 + l15) * TT * NIN + g4 * 8;

  // prologue: x/noise for t=0 (plain loads), convert to f16 fragments
  half8 xh0[4], xh1[4];
  f32x4 nv0, nv1;
  #pragma unroll
  for (int m = 0; m < 4; ++m) {
    xh0[m] = cvt8(*(const f32x4*)xr[m], *(const f32x4*)(xr[m] + 4));
    xh1[m] = cvt8(*(const f32x4*)(xr[m] + 32), *(const f32x4*)(xr[m] + 36));
  }
  nv0 = *(const f32x4*)(noise + cB);
  nv1 = *(const f32x4*)(noise + cB + 16);

  for (int t = 0; t < TT; ++t) {
    f32x4 acc0[4], acc1[4];
    #pragma unroll
    for (int m = 0; m < 4; ++m) {
      acc0[m] = f32x4{0, 0, 0, 0}; acc1[m] = f32x4{0, 0, 0, 0};
    }

    if (t > 0) {
      // ---- proven consume protocol: lanes<16 poll own slot, wave0 fence
      if (wv == 0 && lane < NWG) {
        while (__hip_atomic_load(&flags[lane * 16], __ATOMIC_RELAXED,
                                 __HIP_MEMORY_SCOPE_AGENT) < t) { }
      }
      if (wv == 0)
        __builtin_amdgcn_fence(__ATOMIC_ACQUIRE, "agent");  // 1 inv per WG
      __syncthreads();

      // ---- A-tile: [64 batch][1024] f16, 4 m-tiles, pipelined blocks
      const _Float16* ab[4];
      #pragma unroll
      for (int m = 0; m < 4; ++m)
        ab[m] = th + (t & 1) * 65536 + (m * 16 + l15) * 1024 + g4 * 8;

      half8 A[3][8];
      ISSUE(0, 0); ISSUE(1, 1);
      STEPB(0, 8);  STEPB(1, 8);  STEPB(2, 8);  STEPB(3, 8);
      STEPB(4, 8);  STEPB(5, 8);  STEPB(6, 8);  STEPB(7, 8);
      STEPB(8, 8);  STEPB(9, 8);  STEPB(10, 8); STEPB(11, 8);
      STEPB(12, 8); STEPB(13, 8); STEPB(14, 8); STEPB(15, 0);
    }

    // ---- x part (K chunks 32,33; prefetched f16 frags, zero load latency)
    {
      half8 wa0 = *(const half8*)(whp0 + 32 * 2048);
      half8 wa1 = *(const half8*)(whp1 + 32 * 2048);
      half8 wb0 = *(const half8*)(whp0 + 33 * 2048);
      half8 wb1 = *(const half8*)(whp1 + 33 * 2048);
      #pragma unroll
      for (int m = 0; m < 4; ++m) {
        acc0[m] = MFMA16(wa0, xh0[m], acc0[m], 0, 0, 0);
        acc1[m] = MFMA16(wa1, xh0[m], acc1[m], 0, 0, 0);
        acc0[m] = MFMA16(wb0, xh1[m], acc0[m], 0, 0, 0);
        acc1[m] = MFMA16(wb1, xh1[m], acc1[m], 0, 0, 0);
      }
    }

    // ---- prefetch x/noise for t+1 (latency hides under tanh + drain)
    f32x4 px[4][4], pn0, pn1;
    {
      const int tt = (t + 1 < TT) ? t + 1 : t;
      #pragma unroll
      for (int m = 0; m < 4; ++m) {
        const float* xp = xr[m] + (size_t)tt * NIN;
        LDA16(px[m][0], xp, 0);   LDA16(px[m][1], xp, 16);
        LDA16(px[m][2], xp, 128); LDA16(px[m][3], xp, 144);
      }
      const float* np = noise + (size_t)tt * NRECN + cB;
      LDA16(pn0, np, 0); LDA16(pn1, np, 64);
    }

    // ---- epilogue: h, tanh, coalesced sc1 publish (all 64 rows valid)
    _Float16* ob = th + ((t + 1) & 1) * 65536;
    f32x4 h0[4], h1[4];
    #pragma unroll
    for (int m = 0; m < 4; ++m) {
      #pragma unroll
      for (int r = 0; r < 4; ++r) {
        h0[m][r] = acc0[m][r] + nv0[r] * NOISE_STD;
        h1[m][r] = acc1[m][r] + nv1[r] * NOISE_STD;
      }
      float tv0[4], tv1[4];
      #pragma unroll
      for (int r = 0; r < 4; ++r) {
        tv0[r] = 1.f - 2.f / (__expf(2.f * h0[m][r]) + 1.f);
        tv1[r] = 1.f - 2.f / (__expf(2.f * h1[m][r]) + 1.f);
      }
      u32x2 w0, w1;
      w0[0] = pk2h(tv0[0], tv0[1]); w0[1] = pk2h(tv0[2], tv0[3]);
      w1[0] = pk2h(tv1[0], tv1[1]); w1[1] = pk2h(tv1[2], tv1[3]);
      st_d2_sc1(ob + (m * 16 + l15) * 1024 + cB, w0);
      st_d2_sc1(ob + (m * 16 + l15) * 1024 + cB + 16, w1);
    }
    WAITV(0);          // publish + prefetch committed in this wave
    // convert prefetched x to f16 frags (prefetch regs now valid)
    #pragma unroll
    for (int m = 0; m < 4; ++m) {
      xh0[m] = cvt8(px[m][0], px[m][1]);
      xh1[m] = cvt8(px[m][2], px[m][3]);
    }
    nv0 = pn0; nv1 = pn1;
    __syncthreads();   // both waves drained -> WG's th fully visible
    if (tid == 0)
      __hip_atomic_fetch_add(&flags[wg * 16], 1, __ATOMIC_RELAXED,
                             __HIP_MEMORY_SCOPE_AGENT);

    // ---- outputs, off the critical path (after post)
    if (l15 == 15) {                             // m=3,l15=15 -> batch 63
      #pragma unroll
      for (int r = 0; r < 4; ++r) {
        out[(size_t)(cB + r) * TT + t] = h0[3][r];
        out[(size_t)(cB + 16 + r) * TT + t] = h1[3][r];
      }
    }
    if (t == TT - 1) {                           // final h, coalesced f32x4
      #pragma unroll
      for (int m = 0; m < 4; ++m) {
        const int br = m * 16 + l15;
        *(f32x4*)(out + (size_t)NRECN * TT + (size_t)br * NRECN + cB) = h0[m];
        *(f32x4*)(out + (size_t)NRECN * TT + (size_t)br * NRECN + cB + 16) = h1[m];
      }
    }
  }
}

extern "C" void kernel_launch(void* const* d_in, const int* in_sizes, int n_in,
                              void* d_out, int out_size, void* d_ws, size_t ws_size,
                              hipStream_t stream) {
  const float* x     = (const float*)d_in[0];
  const float* W_ih  = (const float*)d_in[1];
  const float* W_hh  = (const float*)d_in[2];
  const float* noise = (const float*)d_in[3];
  float* out = (float*)d_out;

  char* ws = (char*)d_ws;
  int* flags = (int*)ws;                         // 16 slots, 64B apart
  _Float16* th = (_Float16*)(ws + 4096);         // [2][64][1024] f16 = 256 KB
  // ws usage: 4096 + 262144 = 266,240 bytes. th is fully rewritten each step
  // before being read (all 1024 cols x 64 rows) -> no th memset needed.

  (void)hipMemsetAsync(flags, 0, 4096, stream);  // deterministic replays

  const size_t lds_bytes = (size_t)136 * 64 * 8 * sizeof(_Float16); // 139,264
  (void)hipFuncSetAttribute((const void*)rnn_scan_kernel,
                            hipFuncAttributeMaxDynamicSharedMemorySize,
                            (int)lds_bytes);

  rnn_scan_kernel<<<dim3(NWG), dim3(128), lds_bytes, stream>>>(
      x, W_ih, W_hh, noise, out, flags, th);
}